// Round 3
// baseline (685.225 us; speedup 1.0000x reference)
//
#include <hip/hip_runtime.h>
#include <stdint.h>

typedef unsigned short u16;
typedef unsigned int   u32;
typedef __attribute__((ext_vector_type(8))) short  short8;   // 8 x bf16 (4 VGPRs)
typedef __attribute__((ext_vector_type(4))) float  floatx4;  // MFMA acc

__device__ __forceinline__ u16 f32_to_bf16(float f) {
  u32 u = __builtin_bit_cast(u32, f);
  u = (u + 0x7fffu + ((u >> 16) & 1u)) >> 16;
  return (u16)u;
}
__device__ __forceinline__ float bf16_to_f32(u16 h) {
  u32 u = ((u32)h) << 16;
  return __builtin_bit_cast(float, u);
}

// async global->LDS, 16B per lane. LDS dst = wave-uniform base + lane*16.
__device__ __forceinline__ void load_lds16(const u16* g, u16* l) {
  auto gp = (const __attribute__((address_space(1))) u32*)(uintptr_t)g;
  auto lp = (__attribute__((address_space(3))) u32*)(u32)(uintptr_t)l;
  __builtin_amdgcn_global_load_lds(gp, lp, 16, 0, 0);
}

// ---------------------------------------------------------------------------
// init: zero the grid-barrier counters (d_ws is poisoned 0xAA each call)
// ---------------------------------------------------------------------------
__global__ void init_ctr(u32* ctr) { if (threadIdx.x < 16) ctr[threadIdx.x] = 0; }

// Device-scope grid barrier: one counter per barrier (no reuse -> no sense flip).
// All 512 blocks are co-resident (launch_bounds(256,2) + LDS 48KB -> >=2 blk/CU).
__device__ __forceinline__ void grid_barrier(u32* ctr, u32 target) {
  __syncthreads();
  if (threadIdx.x == 0) {
    __threadfence();  // release: drain + make this block's writes visible
    __hip_atomic_fetch_add(ctr, 1u, __ATOMIC_ACQ_REL, __HIP_MEMORY_SCOPE_AGENT);
    while (__hip_atomic_load(ctr, __ATOMIC_ACQUIRE, __HIP_MEMORY_SCOPE_AGENT) < target)
      __builtin_amdgcn_s_sleep(2);
    __threadfence();  // acquire: invalidate caches before reading others' data
  }
  __syncthreads();
}

// ---------------------------------------------------------------------------
// Phase 0: fused QKV 1x1 conv + patch-token layout (identical math to R2,
// 1024 virtual threads = 4 iterations of 256 real threads).
// qt,kt: [b][n][m] bf16 ; v: [b][m][n] bf16
// ---------------------------------------------------------------------------
__device__ __forceinline__ void qkv_phase(
    char* pool, int bx, int t, const float* __restrict__ x,
    const float* __restrict__ Wq, const float* __restrict__ bq,
    const float* __restrict__ Wk, const float* __restrict__ bk,
    const float* __restrict__ Wv, const float* __restrict__ bv,
    u16* __restrict__ qt, u16* __restrict__ kt, u16* __restrict__ vm)
{
  u16* qs  = (u16*)pool;        // [128][64]
  u16* ks_ = qs + 8192;
  u16* vs  = ks_ + 8192;        // [64][128]

  const int wq = bx & 7, g = (bx >> 3) & 7, b = bx >> 6;

#pragma unroll
  for (int i = 0; i < 4; i++) {
    const int vt = t + i * 256;
    const int lw = vt >> 5, lh = vt & 31;
    const int w  = wq * 32 + lw;
    const int h  = g * 16 + (lh & 15) + ((lh >> 4) << 7);
    const int nl = ((lh >> 3) & 1) * 64 + (lw & 7) * 8 + (lh & 7);
    const int mc = ((lw >> 3) << 1) + (lh >> 4);

    float aq[8], ak[8], av[8];
#pragma unroll
    for (int j = 0; j < 8; j++) { aq[j] = 0.f; ak[j] = 0.f; av[j] = 0.f; }

    const float* xp = x + (size_t)b * 64 * 65536 + w * 256 + h;
#pragma unroll 4
    for (int c = 0; c < 64; c++) {
      float xv = xp[c * 65536];
#pragma unroll
      for (int cq = 0; cq < 8; cq++) {
        aq[cq] = fmaf(Wq[cq * 64 + c], xv, aq[cq]);
        ak[cq] = fmaf(Wk[cq * 64 + c], xv, ak[cq]);
        av[cq] = fmaf(Wv[cq * 64 + c], xv, av[cq]);
      }
    }
#pragma unroll
    for (int cq = 0; cq < 8; cq++) {
      qs[nl * 64 + cq * 8 + mc]    = f32_to_bf16(aq[cq] + bq[cq]);
      ks_[nl * 64 + cq * 8 + mc]   = f32_to_bf16(ak[cq] + bk[cq]);
      vs[(cq * 8 + mc) * 128 + nl] = f32_to_bf16(av[cq] + bv[cq]);
    }
  }
  __syncthreads();

#pragma unroll
  for (int i = 0; i < 4; i++) {
    const int vt = t + i * 256;
    {
      const int nl2 = vt >> 3, cq2 = vt & 7;
      const size_t row = (size_t)b * 1024 + g * 128 + nl2;
      uint4 vq = *(const uint4*)(qs + nl2 * 64 + cq2 * 8);
      uint4 vk = *(const uint4*)(ks_ + nl2 * 64 + cq2 * 8);
      *(uint4*)(qt + row * 512 + cq2 * 64 + wq * 8) = vq;
      *(uint4*)(kt + row * 512 + cq2 * 64 + wq * 8) = vk;
    }
    {
      const int pr = vt >> 4, l16 = vt & 15;
      const int cq3 = pr >> 3, mc3 = pr & 7;
      const int mrow = cq3 * 64 + wq * 8 + mc3;
      uint4 vv = *(const uint4*)(vs + pr * 128 + l16 * 8);
      *(uint4*)(vm + ((size_t)b * 512 + mrow) * 1024 + g * 128 + l16 * 8) = vv;
    }
  }
}

// ---------------------------------------------------------------------------
// NT GEMM phase: C[M][N] = scale * A[M][K] * B[N][K]^T. Tile 64x128, BK=64.
// XOR-swizzled LDS (R2): staging swizzles the global source chunk; readers
// XOR the chunk index -> 2-way bank access (free).
// ---------------------------------------------------------------------------
__device__ __forceinline__ void gemm_phase(
    char* pool, int t,
    const u16* __restrict__ A, const u16* __restrict__ Bm, u16* __restrict__ Cm,
    int M, int N, int K, float scale, int bm, int bn, int bz)
{
  u16* As = (u16*)pool;        // 64*64
  u16* Bs = As + 4096;         // 128*64

  const int lane = t & 63, wid = t >> 6;
  const int wm = wid & 1, wn = wid >> 1;
  const int m0 = bm * 64, n0 = bn * 128;

  const u16* Ab = A + (size_t)bz * M * K + (size_t)m0 * K;
  const u16* Bb = Bm + (size_t)bz * N * K + (size_t)n0 * K;

  floatx4 acc[2][4];
#pragma unroll
  for (int i = 0; i < 2; i++)
#pragma unroll
    for (int j = 0; j < 4; j++) acc[i][j] = (floatx4){0.f, 0.f, 0.f, 0.f};

  const int srow = wid * 8 + (lane >> 3);
  const int scol = (((lane & 7) ^ ((lane >> 3) & 7)) << 3);
  const int l15 = lane & 15, quad = lane >> 4;
  const int cxor = (l15 & 7) << 3;

  for (int k0 = 0; k0 < K; k0 += 64) {
#pragma unroll
    for (int i = 0; i < 2; i++)
      load_lds16(Ab + (size_t)(i * 32 + srow) * K + k0 + scol, As + (i * 32 + wid * 8) * 64);
#pragma unroll
    for (int i = 0; i < 4; i++)
      load_lds16(Bb + (size_t)(i * 32 + srow) * K + k0 + scol, Bs + (i * 32 + wid * 8) * 64);
    __syncthreads();
#pragma unroll
    for (int ks = 0; ks < 2; ks++) {
      const int koff = (ks * 32 + quad * 8) ^ cxor;
      short8 a[2], b[4];
#pragma unroll
      for (int f = 0; f < 2; f++)
        a[f] = *(const short8*)(As + (wm * 32 + f * 16 + l15) * 64 + koff);
#pragma unroll
      for (int f = 0; f < 4; f++)
        b[f] = *(const short8*)(Bs + (wn * 64 + f * 16 + l15) * 64 + koff);
#pragma unroll
      for (int fm = 0; fm < 2; fm++)
#pragma unroll
        for (int fn = 0; fn < 4; fn++)
          acc[fm][fn] = __builtin_amdgcn_mfma_f32_16x16x32_bf16(a[fm], b[fn], acc[fm][fn], 0, 0, 0);
    }
    __syncthreads();
  }

  u16* Cb = Cm + (size_t)bz * M * N;
#pragma unroll
  for (int fm = 0; fm < 2; fm++)
#pragma unroll
    for (int fn = 0; fn < 4; fn++)
#pragma unroll
      for (int r = 0; r < 4; r++) {
        int row = m0 + wm * 32 + fm * 16 + quad * 4 + r;
        int col = n0 + wn * 64 + fn * 16 + l15;
        Cb[(size_t)row * N + col] = f32_to_bf16(scale * acc[fm][fn][r]);
      }
}

// ---------------------------------------------------------------------------
// Softmax phase: one 1024-wide row per iteration, in place on EP (bf16).
// ---------------------------------------------------------------------------
__device__ __forceinline__ void softmax_row(char* pool, int t, u16* __restrict__ row)
{
  float* redm = (float*)pool;        // [4]
  float* reds = redm + 4;            // [4]
  const int lane = t & 63, wid = t >> 6;

  ushort4 hv = ((const ushort4*)row)[t];
  float e[4] = {bf16_to_f32(hv.x), bf16_to_f32(hv.y), bf16_to_f32(hv.z), bf16_to_f32(hv.w)};

  float mx = fmaxf(fmaxf(e[0], e[1]), fmaxf(e[2], e[3]));
#pragma unroll
  for (int off = 32; off > 0; off >>= 1) mx = fmaxf(mx, __shfl_xor(mx, off));
  if (lane == 0) redm[wid] = mx;
  __syncthreads();
  mx = fmaxf(fmaxf(redm[0], redm[1]), fmaxf(redm[2], redm[3]));

  float s = 0.f;
#pragma unroll
  for (int i = 0; i < 4; i++) { e[i] = __expf(e[i] - mx); s += e[i]; }
#pragma unroll
  for (int off = 32; off > 0; off >>= 1) s += __shfl_xor(s, off);
  if (lane == 0) reds[wid] = s;
  __syncthreads();
  s = reds[0] + reds[1] + reds[2] + reds[3];

  float inv = 1.0f / s;
  hv.x = f32_to_bf16(e[0] * inv);
  hv.y = f32_to_bf16(e[1] * inv);
  hv.z = f32_to_bf16(e[2] * inv);
  hv.w = f32_to_bf16(e[3] * inv);
  ((ushort4*)row)[t] = hv;
}

// ---------------------------------------------------------------------------
// Out phase: out = gamma*(Wo . OT + bo) + x
// ---------------------------------------------------------------------------
__device__ __forceinline__ void out_phase(
    int pix, const float* __restrict__ x, const u16* __restrict__ OT,
    const float* __restrict__ Wo, const float* __restrict__ bo,
    float g, float* __restrict__ out)
{
  const int b = pix >> 16, rem = pix & 65535;
  const u16* otb = OT + (size_t)b * 524288;
  const int m = rem & 511;
  const int nbase = rem >> 9;
  float oc[8];
#pragma unroll
  for (int cq = 0; cq < 8; cq++)
    oc[cq] = bf16_to_f32(otb[(size_t)(cq * 128 + nbase) * 512 + m]);

  const float* xb = x + (size_t)b * 4194304 + rem;
  float* ob = out + (size_t)b * 4194304 + rem;
#pragma unroll 4
  for (int o = 0; o < 64; o++) {
    float acc = bo[o];
#pragma unroll
    for (int cq = 0; cq < 8; cq++) acc = fmaf(Wo[o * 8 + cq], oc[cq], acc);
    ob[o * 65536] = fmaf(g, acc, xb[o * 65536]);
  }
}

// ---------------------------------------------------------------------------
// MEGA: all 5 phases, grid 512 x 256, device-scope barriers between phases.
// ---------------------------------------------------------------------------
__global__ __launch_bounds__(256, 2) void mega_kernel(
    const float* __restrict__ x,
    const float* __restrict__ Wq, const float* __restrict__ bq,
    const float* __restrict__ Wk, const float* __restrict__ bk,
    const float* __restrict__ Wv, const float* __restrict__ bv,
    const float* __restrict__ Wo, const float* __restrict__ bo,
    const float* __restrict__ gammap,
    u16* __restrict__ qt, u16* __restrict__ kt, u16* __restrict__ vm,
    u16* __restrict__ EP, u32* __restrict__ ctr, float* __restrict__ out)
{
  __shared__ __align__(16) char pool[49152];
  const int bx = blockIdx.x, t = threadIdx.x;
  u16* OT = qt;   // qt dead after gemm1

  // P0: qkv
  qkv_phase(pool, bx, t, x, Wq, bq, Wk, bk, Wv, bv, qt, kt, vm);
  grid_barrier(ctr + 0, 512);

  // P1: E = qt*kt^T/32  (M=1024,N=1024,K=512) -> 1024 tile jobs, 2 per block
#pragma unroll 1
  for (int rep = 0; rep < 2; rep++) {
    int job = bx + 512 * rep;
    gemm_phase(pool, t, qt, kt, EP, 1024, 1024, 512, 0.03125f,
               (job >> 3) & 15, job & 7, job >> 7);
  }
  grid_barrier(ctr + 1, 512);

  // P2: softmax, 16 rows per block
#pragma unroll 1
  for (int j = 0; j < 16; j++) {
    softmax_row(pool, t, EP + (size_t)(bx * 16 + j) * 1024);
    __syncthreads();
  }
  grid_barrier(ctr + 2, 512);

  // P3: OT = P*v^T  (M=1024,N=512,K=1024) -> 512 tile jobs, 1 per block
  gemm_phase(pool, t, EP, vm, OT, 1024, 512, 1024, 1.0f,
             (bx >> 2) & 15, bx & 3, bx >> 6);
  grid_barrier(ctr + 3, 512);

  // P4: out, 4 pixel-groups per block
  const float g = gammap[0];
#pragma unroll 1
  for (int rep = 0; rep < 4; rep++) {
    int pix = (bx + 512 * rep) * 256 + t;
    out_phase(pix, x, OT, Wo, bo, g, out);
  }
}

// ---------------------------------------------------------------------------
extern "C" void kernel_launch(void* const* d_in, const int* in_sizes, int n_in,
                              void* d_out, int out_size, void* d_ws, size_t ws_size,
                              hipStream_t stream) {
  const float* x  = (const float*)d_in[0];
  const float* Wq = (const float*)d_in[1];
  const float* bq = (const float*)d_in[2];
  const float* Wk = (const float*)d_in[3];
  const float* bk = (const float*)d_in[4];
  const float* Wv = (const float*)d_in[5];
  const float* bv = (const float*)d_in[6];
  const float* Wo = (const float*)d_in[7];
  const float* bo = (const float*)d_in[8];
  const float* gm = (const float*)d_in[9];
  float* out = (float*)d_out;

  u16* qt = (u16*)d_ws;            // 8*1024*512
  u16* kt = qt + 4194304;
  u16* vm = kt + 4194304;
  u16* EP = vm + 4194304;          // 8*1024*1024
  u32* ctr = (u32*)((char*)d_ws + 41943040);  // after EP

  init_ctr<<<1, 16, 0, stream>>>(ctr);
  mega_kernel<<<512, 256, 0, stream>>>(x, Wq, bq, Wk, bk, Wv, bv, Wo, bo, gm,
                                       qt, kt, vm, EP, ctr, out);
}

// Round 4
// 340.829 us; speedup vs baseline: 2.0105x; 2.0105x over previous
//
#include <hip/hip_runtime.h>
#include <stdint.h>

typedef unsigned short u16;
typedef unsigned int   u32;
typedef __attribute__((ext_vector_type(8))) short  short8;   // 8 x bf16 (4 VGPRs)
typedef __attribute__((ext_vector_type(4))) float  floatx4;  // MFMA acc

__device__ __forceinline__ u16 f32_to_bf16(float f) {
  u32 u = __builtin_bit_cast(u32, f);
  u = (u + 0x7fffu + ((u >> 16) & 1u)) >> 16;
  return (u16)u;
}
__device__ __forceinline__ float bf16_to_f32(u16 h) {
  u32 u = ((u32)h) << 16;
  return __builtin_bit_cast(float, u);
}
__device__ __forceinline__ float bf16_lo(u32 u) {  // low half of packed pair
  return __builtin_bit_cast(float, u << 16);
}
__device__ __forceinline__ float bf16_hi(u32 u) {  // high half, no shift needed
  return __builtin_bit_cast(float, u & 0xffff0000u);
}

// async global->LDS, 16B per lane. LDS dst = wave-uniform base + lane*16.
__device__ __forceinline__ void load_lds16(const u16* g, u16* l) {
  auto gp = (const __attribute__((address_space(1))) u32*)(uintptr_t)g;
  auto lp = (__attribute__((address_space(3))) u32*)(u32)(uintptr_t)l;
  __builtin_amdgcn_global_load_lds(gp, lp, 16, 0, 0);
}

// ---------------------------------------------------------------------------
// K1: fused QKV 1x1 conv + patch-token layout. 2 pixels (consecutive h) per
// thread, float2 x-loads. Accumulation order per pixel identical to R2.
// qt,kt: [b][n][m] bf16 ; v: [b][m][n] bf16
// ---------------------------------------------------------------------------
__global__ __launch_bounds__(512) void qkv_kernel(
    const float* __restrict__ x,
    const float* __restrict__ Wq, const float* __restrict__ bq,
    const float* __restrict__ Wk, const float* __restrict__ bk,
    const float* __restrict__ Wv, const float* __restrict__ bv,
    u16* __restrict__ qt, u16* __restrict__ kt, u16* __restrict__ vm)
{
  __shared__ __align__(16) u16 qs[128 * 64];   // [nl][cq*8+mc]
  __shared__ __align__(16) u16 ks_[128 * 64];
  __shared__ __align__(16) u16 vs[64 * 128];   // [cq*8+mc][nl]

  const int wq = blockIdx.x;   // 0..7
  const int g  = blockIdx.y;   // 0..7
  const int b  = blockIdx.z;   // 0..7
  const int t  = threadIdx.x;  // 0..511
  const int vt0 = t << 1;      // even virtual thread; handles vt0, vt0+1
  const int lw = vt0 >> 5, lh = vt0 & 31;      // lh even
  const int w  = wq * 32 + lw;
  const int h  = g * 16 + (lh & 15) + ((lh >> 4) << 7);   // even, pair h,h+1
  const int nl = ((lh >> 3) & 1) * 64 + (lw & 7) * 8 + (lh & 7);  // pair nl,nl+1
  const int mc = ((lw >> 3) << 1) + (lh >> 4);

  float aq[2][8], ak[2][8], av[2][8];
#pragma unroll
  for (int j = 0; j < 2; j++)
#pragma unroll
    for (int i = 0; i < 8; i++) { aq[j][i] = 0.f; ak[j][i] = 0.f; av[j][i] = 0.f; }

  const float* xp = x + (size_t)b * 64 * 65536 + w * 256 + h;
#pragma unroll 4
  for (int c = 0; c < 64; c++) {
    float2 xv = *(const float2*)(xp + c * 65536);
#pragma unroll
    for (int cq = 0; cq < 8; cq++) {
      float wqc = Wq[cq * 64 + c], wkc = Wk[cq * 64 + c], wvc = Wv[cq * 64 + c];
      aq[0][cq] = fmaf(wqc, xv.x, aq[0][cq]);
      ak[0][cq] = fmaf(wkc, xv.x, ak[0][cq]);
      av[0][cq] = fmaf(wvc, xv.x, av[0][cq]);
      aq[1][cq] = fmaf(wqc, xv.y, aq[1][cq]);
      ak[1][cq] = fmaf(wkc, xv.y, ak[1][cq]);
      av[1][cq] = fmaf(wvc, xv.y, av[1][cq]);
    }
  }
#pragma unroll
  for (int j = 0; j < 2; j++)
#pragma unroll
    for (int cq = 0; cq < 8; cq++) {
      qs[(nl + j) * 64 + cq * 8 + mc]    = f32_to_bf16(aq[j][cq] + bq[cq]);
      ks_[(nl + j) * 64 + cq * 8 + mc]   = f32_to_bf16(ak[j][cq] + bk[cq]);
      vs[(cq * 8 + mc) * 128 + nl + j]   = f32_to_bf16(av[j][cq] + bv[cq]);
    }
  __syncthreads();

#pragma unroll
  for (int i = 0; i < 2; i++) {
    const int vt = t + i * 512;
    {
      const int nl2 = vt >> 3, cq2 = vt & 7;
      const size_t row = (size_t)b * 1024 + g * 128 + nl2;
      uint4 vq = *(const uint4*)(qs + nl2 * 64 + cq2 * 8);
      uint4 vk = *(const uint4*)(ks_ + nl2 * 64 + cq2 * 8);
      *(uint4*)(qt + row * 512 + cq2 * 64 + wq * 8) = vq;
      *(uint4*)(kt + row * 512 + cq2 * 64 + wq * 8) = vk;
    }
    {
      const int pr = vt >> 4, l16 = vt & 15;
      const int cq3 = pr >> 3, mc3 = pr & 7;
      const int mrow = cq3 * 64 + wq * 8 + mc3;
      uint4 vv = *(const uint4*)(vs + pr * 128 + l16 * 8);
      *(uint4*)(vm + ((size_t)b * 512 + mrow) * 1024 + g * 128 + l16 * 8) = vv;
    }
  }
}

// ---------------------------------------------------------------------------
// NT GEMM: C[M][N] = scale * A[M][K] * B[N][K]^T  (unchanged from R2)
// Tile BM(=FMW*32) x 128, BK=64, XOR-swizzled LDS.
// ---------------------------------------------------------------------------
template <int FMW>
__global__ __launch_bounds__(256) void gemm_nt(
    const u16* __restrict__ A, const u16* __restrict__ Bm, u16* __restrict__ Cm,
    int M, int N, int K, float scale)
{
  constexpr int BM = FMW * 32;
  __shared__ __align__(16) u16 As[BM * 64];
  __shared__ __align__(16) u16 Bs[128 * 64];

  const int bn = blockIdx.x, bm = blockIdx.y, bz = blockIdx.z;
  const int t = threadIdx.x;
  const int lane = t & 63, wid = t >> 6;
  const int wm = wid & 1, wn = wid >> 1;
  const int m0 = bm * BM, n0 = bn * 128;

  const u16* Ab = A + (size_t)bz * M * K + (size_t)m0 * K;
  const u16* Bb = Bm + (size_t)bz * N * K + (size_t)n0 * K;

  floatx4 acc[FMW][4];
#pragma unroll
  for (int i = 0; i < FMW; i++)
#pragma unroll
    for (int j = 0; j < 4; j++) acc[i][j] = (floatx4){0.f, 0.f, 0.f, 0.f};

  const int srow = wid * 8 + (lane >> 3);
  const int scol = (((lane & 7) ^ ((lane >> 3) & 7)) << 3);
  const int l15 = lane & 15, quad = lane >> 4;
  const int cxor = (l15 & 7) << 3;

  for (int k0 = 0; k0 < K; k0 += 64) {
#pragma unroll
    for (int i = 0; i < FMW; i++)
      load_lds16(Ab + (size_t)(i * 32 + srow) * K + k0 + scol, As + (i * 32 + wid * 8) * 64);
#pragma unroll
    for (int i = 0; i < 4; i++)
      load_lds16(Bb + (size_t)(i * 32 + srow) * K + k0 + scol, Bs + (i * 32 + wid * 8) * 64);
    __syncthreads();
#pragma unroll
    for (int ks = 0; ks < 2; ks++) {
      const int koff = (ks * 32 + quad * 8) ^ cxor;
      short8 a[FMW], b[4];
#pragma unroll
      for (int f = 0; f < FMW; f++)
        a[f] = *(const short8*)(As + (wm * FMW * 16 + f * 16 + l15) * 64 + koff);
#pragma unroll
      for (int f = 0; f < 4; f++)
        b[f] = *(const short8*)(Bs + (wn * 64 + f * 16 + l15) * 64 + koff);
#pragma unroll
      for (int fm = 0; fm < FMW; fm++)
#pragma unroll
        for (int fn = 0; fn < 4; fn++)
          acc[fm][fn] = __builtin_amdgcn_mfma_f32_16x16x32_bf16(a[fm], b[fn], acc[fm][fn], 0, 0, 0);
    }
    __syncthreads();
  }

  u16* Cb = Cm + (size_t)bz * M * N;
#pragma unroll
  for (int fm = 0; fm < FMW; fm++)
#pragma unroll
    for (int fn = 0; fn < 4; fn++)
#pragma unroll
      for (int r = 0; r < 4; r++) {
        int row = m0 + wm * FMW * 16 + fm * 16 + quad * 4 + r;
        int col = n0 + wn * 64 + fn * 16 + l15;
        Cb[(size_t)row * N + col] = f32_to_bf16(scale * acc[fm][fn][r]);
      }
}

// ---------------------------------------------------------------------------
// Softmax: one 1024-wide row per WAVE (shuffle-only, no LDS/syncthreads).
// 4 rows per 256-thread block; uint4 row I/O (16 bf16 per lane).
// ---------------------------------------------------------------------------
__global__ __launch_bounds__(256) void softmax_kernel(u16* __restrict__ EP)
{
  const int lane = threadIdx.x & 63, wid = threadIdx.x >> 6;
  const int r = blockIdx.x * 4 + wid;           // 0..8191
  u32* row = (u32*)(EP + (size_t)r * 1024);     // 512 u32

  uint4 c0 = ((const uint4*)row)[lane];
  uint4 c1 = ((const uint4*)row)[64 + lane];
  u32 u[8] = {c0.x, c0.y, c0.z, c0.w, c1.x, c1.y, c1.z, c1.w};
  float e[16];
#pragma unroll
  for (int i = 0; i < 8; i++) { e[2 * i] = bf16_lo(u[i]); e[2 * i + 1] = bf16_hi(u[i]); }

  float mx = e[0];
#pragma unroll
  for (int i = 1; i < 16; i++) mx = fmaxf(mx, e[i]);
#pragma unroll
  for (int off = 32; off > 0; off >>= 1) mx = fmaxf(mx, __shfl_xor(mx, off));

  float s = 0.f;
#pragma unroll
  for (int i = 0; i < 16; i++) { e[i] = __expf(e[i] - mx); s += e[i]; }
#pragma unroll
  for (int off = 32; off > 0; off >>= 1) s += __shfl_xor(s, off);

  float inv = 1.0f / s;
#pragma unroll
  for (int i = 0; i < 8; i++)
    u[i] = (u32)f32_to_bf16(e[2 * i] * inv) | ((u32)f32_to_bf16(e[2 * i + 1] * inv) << 16);
  ((uint4*)row)[lane]      = (uint4){u[0], u[1], u[2], u[3]};
  ((uint4*)row)[64 + lane] = (uint4){u[4], u[5], u[6], u[7]};
}

// ---------------------------------------------------------------------------
// K5: out = gamma*(Wo . OT + bo) + x. 4 consecutive pixels per thread,
// float4 x-loads / out-stores (1 KB per wave-instruction).
// ---------------------------------------------------------------------------
__global__ __launch_bounds__(256) void out_kernel(
    const float* __restrict__ x, const u16* __restrict__ OT,
    const float* __restrict__ Wo, const float* __restrict__ bo,
    const float* __restrict__ gammap, float* __restrict__ out)
{
  const int tid = blockIdx.x * 256 + threadIdx.x;   // 0..131071
  const int pix = tid << 2;                          // 4-aligned
  const int b = pix >> 16, rem = pix & 65535;
  const float g = gammap[0];

  const u16* otb = OT + (size_t)b * 524288;
  const int m = rem & 511;                           // 4-aligned, no wrap
  const int nbase = rem >> 9;
  float oc[8][4];
#pragma unroll
  for (int cq = 0; cq < 8; cq++) {
    ushort4 hv = *(const ushort4*)(otb + (size_t)(cq * 128 + nbase) * 512 + m);
    oc[cq][0] = bf16_to_f32(hv.x); oc[cq][1] = bf16_to_f32(hv.y);
    oc[cq][2] = bf16_to_f32(hv.z); oc[cq][3] = bf16_to_f32(hv.w);
  }

  const float4* xb4 = (const float4*)(x + (size_t)b * 4194304 + rem);
  float4* ob4 = (float4*)(out + (size_t)b * 4194304 + rem);
#pragma unroll 4
  for (int o = 0; o < 64; o++) {
    float4 xv = xb4[o * 16384];
    float a0 = bo[o], a1 = a0, a2 = a0, a3 = a0;
#pragma unroll
    for (int cq = 0; cq < 8; cq++) {
      float wv = Wo[o * 8 + cq];
      a0 = fmaf(wv, oc[cq][0], a0);
      a1 = fmaf(wv, oc[cq][1], a1);
      a2 = fmaf(wv, oc[cq][2], a2);
      a3 = fmaf(wv, oc[cq][3], a3);
    }
    float4 r;
    r.x = fmaf(g, a0, xv.x); r.y = fmaf(g, a1, xv.y);
    r.z = fmaf(g, a2, xv.z); r.w = fmaf(g, a3, xv.w);
    ob4[o * 16384] = r;
  }
}

// ---------------------------------------------------------------------------
extern "C" void kernel_launch(void* const* d_in, const int* in_sizes, int n_in,
                              void* d_out, int out_size, void* d_ws, size_t ws_size,
                              hipStream_t stream) {
  const float* x  = (const float*)d_in[0];
  const float* Wq = (const float*)d_in[1];
  const float* bq = (const float*)d_in[2];
  const float* Wk = (const float*)d_in[3];
  const float* bk = (const float*)d_in[4];
  const float* Wv = (const float*)d_in[5];
  const float* bv = (const float*)d_in[6];
  const float* Wo = (const float*)d_in[7];
  const float* bo = (const float*)d_in[8];
  const float* gm = (const float*)d_in[9];
  float* out = (float*)d_out;

  // workspace carve: qt | kt | v | EP ; OT reuses qt (dead after gemm1)
  u16* qt = (u16*)d_ws;            // 8*1024*512
  u16* kt = qt + 4194304;
  u16* vm = kt + 4194304;
  u16* EP = vm + 4194304;          // 8*1024*1024
  u16* OT = qt;                    // reuse

  qkv_kernel<<<dim3(8, 8, 8), 512, 0, stream>>>(x, Wq, bq, Wk, bk, Wv, bv, qt, kt, vm);
  // E = qt * kt^T / 32   (M=1024, N=1024, K=512), 128x128 tiles
  gemm_nt<4><<<dim3(8, 8, 8), 256, 0, stream>>>(qt, kt, EP, 1024, 1024, 512, 0.03125f);
  softmax_kernel<<<2048, 256, 0, stream>>>(EP);
  // OT[j][m] = P * v^T   (M=1024, N=512, K=1024), 64x128 tiles
  gemm_nt<2><<<dim3(4, 16, 8), 256, 0, stream>>>(EP, vm, OT, 1024, 512, 1024, 1.0f);
  out_kernel<<<512, 256, 0, stream>>>(x, OT, Wo, bo, gm, out);
}